// Round 3
// baseline (108.886 us; speedup 1.0000x reference)
//
#include <hip/hip_runtime.h>
#include <cstdint>
#include <cstddef>

typedef __attribute__((ext_vector_type(4))) float  f32x4;
typedef __attribute__((ext_vector_type(8))) short  short8;
typedef __attribute__((ext_vector_type(4))) short  short4v;

__device__ __forceinline__ short f2bf(float f) {
  unsigned u = __float_as_uint(f);
  u += 0x7FFF + ((u >> 16) & 1);   // round-to-nearest-even
  return (short)(u >> 16);
}
__device__ __forceinline__ float sigmoidf(float x) {
  return 1.0f / (1.0f + __expf(-x));
}

// ---------------- pool: g[b,c] = mean_s x[b,c,s], one wave per row ----------
__global__ __launch_bounds__(256) void pool_kernel(const float* __restrict__ x,
                                                   float* __restrict__ g,
                                                   int nrows) {
  int gid  = blockIdx.x * 256 + threadIdx.x;
  int row  = gid >> 6;
  int lane = threadIdx.x & 63;
  if (row >= nrows) return;
  float s = 0.f;
  if (lane < 49) {                       // 196 floats = 49 float4
    const float4* p = (const float4*)(x + (size_t)row * 196);
    float4 v = p[lane];
    s = v.x + v.y + v.z + v.w;
  }
#pragma unroll
  for (int off = 32; off > 0; off >>= 1) s += __shfl_down(s, off);
  if (lane == 0) g[row] = s * (1.0f / 196.0f);
}

// --------- GEMM (BT layout, M=64, BN=64) with K-split, bf16 MFMA ------------
// out_part[ks][m][n] = sum_{k in chunk ks} A[m,k] * B[n,k]
template<int N, int K, int KCHUNK>
__global__ __launch_bounds__(256) void gemm_bt_part(const float* __restrict__ A,
                                                    const float* __restrict__ B,
                                                    float* __restrict__ part) {
  constexpr int BM = 64, BN = 64, BK = 64;
  constexpr int NT = N / BN;
  const int nt = blockIdx.x % NT;
  const int ks = blockIdx.x / NT;
  const int n0 = nt * BN;
  const int k0 = ks * KCHUNK;

  __shared__ short As[BM * BK];   // bf16, XOR-swizzled rows of 128B
  __shared__ short Bs[BN * BK];

  const int tid  = threadIdx.x;
  const int lane = tid & 63;
  const int wv   = tid >> 6;
  const int wm   = wv >> 1, wn = wv & 1;   // 2x2 wave grid, each 32x32

  f32x4 acc[2][2] = {};

  for (int t = 0; t < KCHUNK / BK; ++t) {
    const int kt = k0 + t * BK;
    __syncthreads();
    // stage A: 64x64 f32 -> bf16 (1024 float4, 4/thread)
#pragma unroll
    for (int i = 0; i < 4; ++i) {
      int f = i * 256 + tid;
      int row = f >> 4, c4 = f & 15;
      float4 v = *(const float4*)(A + (size_t)row * K + kt + c4 * 4);
      short4v sv; sv.x = f2bf(v.x); sv.y = f2bf(v.y); sv.z = f2bf(v.z); sv.w = f2bf(v.w);
      int bo = (c4 * 8) ^ ((row & 7) << 4);
      *(short4v*)(As + row * 64 + (bo >> 1)) = sv;
    }
    // stage B: 64x64 f32 -> bf16 (1024 float4, 4/thread)
#pragma unroll
    for (int i = 0; i < 4; ++i) {
      int f = i * 256 + tid;
      int row = f >> 4, c4 = f & 15;
      float4 v = *(const float4*)(B + (size_t)(n0 + row) * K + kt + c4 * 4);
      short4v sv; sv.x = f2bf(v.x); sv.y = f2bf(v.y); sv.z = f2bf(v.z); sv.w = f2bf(v.w);
      int bo = (c4 * 8) ^ ((row & 7) << 4);
      *(short4v*)(Bs + row * 64 + (bo >> 1)) = sv;
    }
    __syncthreads();
#pragma unroll
    for (int kk = 0; kk < 2; ++kk) {
      const int kbyte = kk * 64 + ((lane >> 4) << 4);
      short8 af[2], bf[2];
#pragma unroll
      for (int mi = 0; mi < 2; ++mi) {
        int row = wm * 32 + mi * 16 + (lane & 15);
        int bo  = kbyte ^ ((row & 7) << 4);
        af[mi]  = *(const short8*)(As + row * 64 + (bo >> 1));
      }
#pragma unroll
      for (int ni = 0; ni < 2; ++ni) {
        int row = wn * 32 + ni * 16 + (lane & 15);
        int bo  = kbyte ^ ((row & 7) << 4);
        bf[ni]  = *(const short8*)(Bs + row * 64 + (bo >> 1));
      }
#pragma unroll
      for (int mi = 0; mi < 2; ++mi)
#pragma unroll
        for (int ni = 0; ni < 2; ++ni)
          acc[mi][ni] = __builtin_amdgcn_mfma_f32_16x16x32_bf16(af[mi], bf[ni], acc[mi][ni], 0, 0, 0);
    }
  }
  // write f32 partial tile (C/D layout: row=(lane>>4)*4+r, col=lane&15)
  float* pp = part + (size_t)ks * BM * N;
#pragma unroll
  for (int mi = 0; mi < 2; ++mi)
#pragma unroll
    for (int ni = 0; ni < 2; ++ni)
#pragma unroll
      for (int r = 0; r < 4; ++r) {
        int m = wm * 32 + mi * 16 + ((lane >> 4) << 2) + r;
        int n = n0 + wn * 32 + ni * 16 + (lane & 15);
        pp[(size_t)m * N + n] = acc[mi][ni][r];
      }
}

// --------- reduce K-split partials + bias + sigmoid (GEMM1 only) ------------
template<int KS>
__global__ __launch_bounds__(256) void bias_sigmoid_reduce(const float* __restrict__ part,
                                                           const float* __restrict__ bias,
                                                           float* __restrict__ out,
                                                           int MN, int N) {
  int i = blockIdx.x * 256 + threadIdx.x;
  int e = i * 4;
  if (e >= MN) return;
  float4 s = {0.f, 0.f, 0.f, 0.f};
#pragma unroll
  for (int k = 0; k < KS; ++k) {
    float4 v = *(const float4*)(part + (size_t)k * MN + e);
    s.x += v.x; s.y += v.y; s.z += v.z; s.w += v.w;
  }
  float4 b = *(const float4*)(bias + (e % N));
  s.x = sigmoidf(s.x + b.x);
  s.y = sigmoidf(s.y + b.y);
  s.z = sigmoidf(s.z + b.z);
  s.w = sigmoidf(s.w + b.w);
  *(float4*)(out + e) = s;
}

// --------- fused: GEMM2-reduce + bias + sigmoid + einsum partials -----------
// grid = 64 batches x 16 c-chunks of 128.
// Per block: w[b, p, cc*128+c] = sigmoid(b2 + sum_ks part), write wout + LDS;
// then fpart[(b*16+cc)*4+p][s] = sum_c w * x.
__global__ __launch_bounds__(256) void einsum_fused(const float* __restrict__ x,
                                                    const float* __restrict__ part,
                                                    const float* __restrict__ b2,
                                                    float* __restrict__ wout,
                                                    float* __restrict__ fpart) {
  const int b  = blockIdx.x >> 4;
  const int cc = blockIdx.x & 15;
  __shared__ float gs[4 * 128];
  const int tid = threadIdx.x;
#pragma unroll
  for (int i = 0; i < 2; ++i) {
    int idx = i * 256 + tid;              // p*128 + c
    int p = idx >> 7, c = idx & 127;
    int n = p * 2048 + cc * 128 + c;
    float s = 0.f;
#pragma unroll
    for (int ks = 0; ks < 8; ++ks)
      s += part[(size_t)ks * 64 * 8192 + (size_t)b * 8192 + n];
    s = sigmoidf(s + b2[n]);
    wout[(size_t)b * 8192 + n] = s;
    gs[idx] = s;
  }
  __syncthreads();
  if (tid < 196) {
    const float* xp = x + (size_t)b * 2048 * 196 + (size_t)cc * 128 * 196 + tid;
    float a0 = 0, a1 = 0, a2 = 0, a3 = 0;
#pragma unroll 8
    for (int c = 0; c < 128; ++c) {
      float xv = xp[(size_t)c * 196];
      a0 += gs[c]        * xv;
      a1 += gs[128 + c]  * xv;
      a2 += gs[256 + c]  * xv;
      a3 += gs[384 + c]  * xv;
    }
    float* fp = fpart + ((size_t)(b * 16 + cc) * 4) * 196 + tid;
    fp[0]   = a0;
    fp[196] = a1;
    fp[392] = a2;
    fp[588] = a3;
  }
}

// --------- reduce einsum c-chunk partials, scale by 1/C ---------------------
__global__ __launch_bounds__(256) void feat_reduce(const float* __restrict__ fpart,
                                                   float* __restrict__ feat) {
  int i = blockIdx.x * 256 + threadIdx.x;   // 64*4*196 = 50176 elems
  if (i >= 64 * 4 * 196) return;
  int s = i % 196;
  int p = (i / 196) & 3;
  int b = i / 784;
  float sum = 0.f;
#pragma unroll
  for (int cc = 0; cc < 16; ++cc)
    sum += fpart[((size_t)(b * 16 + cc) * 4 + p) * 196 + s];
  feat[i] = sum * (1.0f / 2048.0f);
}

extern "C" void kernel_launch(void* const* d_in, const int* in_sizes, int n_in,
                              void* d_out, int out_size, void* d_ws, size_t ws_size,
                              hipStream_t stream) {
  const float* x  = (const float*)d_in[0];   // [64,2048,14,14]
  const float* w1 = (const float*)d_in[1];   // [4096,2048]
  const float* b1 = (const float*)d_in[2];   // [4096]
  const float* w2 = (const float*)d_in[3];   // [8192,4096]
  const float* b2 = (const float*)d_in[4];   // [8192]
  float* out = (float*)d_out;

  float* g     = (float*)d_ws;               // 64*2048
  float* h     = g + 64 * 2048;              // 64*4096
  float* part  = h + 64 * 4096;              // max(16*64*4096, 8*64*8192) = 4,194,304 floats
  float* fpart = part + 4194304;             // 64*16*4*196 = 802,816 floats

  float* wout = out;                         // [64, 8192] == [B,P,C] flat
  float* feat = out + 524288;                // [64, 4, 196]

  // 1) pool
  pool_kernel<<<(64 * 2048) / 4, 256, 0, stream>>>(x, g, 64 * 2048);

  // 2) GEMM1: h = sigmoid(g @ w1^T + b1)   (N=4096, K=2048, BN=64, 16-way K-split)
  gemm_bt_part<4096, 2048, 128><<<(4096 / 64) * 16, 256, 0, stream>>>(g, w1, part);
  bias_sigmoid_reduce<16><<<(64 * 4096 / 4) / 256, 256, 0, stream>>>(part, b1, h, 64 * 4096, 4096);

  // 3) GEMM2: w-partials (N=8192, K=4096, BN=64, 8-way K-split)
  gemm_bt_part<8192, 4096, 512><<<(8192 / 64) * 8, 256, 0, stream>>>(h, w2, part);

  // 4) fused GEMM2-reduce + sigmoid + einsum partials
  einsum_fused<<<64 * 16, 256, 0, stream>>>(x, part, b2, wout, fpart);

  // 5) reduce einsum partials -> feat
  feat_reduce<<<(50176 + 255) / 256, 256, 0, stream>>>(fpart, feat);
}

// Round 5
// 104.997 us; speedup vs baseline: 1.0370x; 1.0370x over previous
//
#include <hip/hip_runtime.h>
#include <cstdint>
#include <cstddef>

typedef __attribute__((ext_vector_type(4))) float  f32x4;
typedef __attribute__((ext_vector_type(8))) short  short8;

__device__ __forceinline__ short f2bf(float f) {
  unsigned u = __float_as_uint(f);
  u += 0x7FFF + ((u >> 16) & 1);   // round-to-nearest-even
  return (short)(u >> 16);
}
__device__ __forceinline__ float sigmoidf(float x) {
  return 1.0f / (1.0f + __expf(-x));
}

// ---------------- pool: g[b,c] = mean_s x[b,c,s] -> bf16 --------------------
// one wave per row (row = (b,c) pair), 4 rows per 256-thread block
__global__ __launch_bounds__(256) void pool_kernel(const float* __restrict__ x,
                                                   short* __restrict__ g,
                                                   int nrows) {
  int gid  = blockIdx.x * 256 + threadIdx.x;
  int row  = gid >> 6;
  int lane = threadIdx.x & 63;
  if (row >= nrows) return;
  float s = 0.f;
  if (lane < 49) {                       // 196 floats = 49 float4
    const float4* p = (const float4*)(x + (size_t)row * 196);
    float4 v = p[lane];
    s = v.x + v.y + v.z + v.w;
  }
#pragma unroll
  for (int off = 32; off > 0; off >>= 1) s += __shfl_down(s, off);
  if (lane == 0) g[row] = f2bf(s * (1.0f / 196.0f));
}

// --------- barrier-free GEMM: out[m,n] = act(sum_k A[m,k]*B[n,k] + bias) ----
// A: [64][K] bf16 (L2-resident), B: [N][K] f32 (streamed direct to regs).
// Block = 512 threads = 8 waves; block owns 16 n-columns; K split 8-way
// across waves; LDS reduce + bias + sigmoid epilogue. No HBM partials.
template<int N, int K, bool OUT_BF16>
__global__ __launch_bounds__(512, 4) void gemm_fused(const short* __restrict__ A,
                                                     const float* __restrict__ B,
                                                     const float* __restrict__ bias,
                                                     void* __restrict__ outp) {
  constexpr int KW = K / 8;        // k-range per wave
  constexpr int NK = KW / 32;      // MFMA k-steps per wave
  const int n0  = blockIdx.x * 16;
  const int tid = threadIdx.x;
  const int l   = tid & 63;
  const int wv  = tid >> 6;
  const int kw0 = wv * KW;

  __shared__ float red[8 * 1024];  // [wave][m*16+n] f32

  const int ko = (l >> 4) * 8;     // k-offset within 32-k step (operand layout)
  const float* Bp = B + (size_t)(n0 + (l & 15)) * K + kw0 + ko;
  const short* Ap = A + (size_t)(l & 15) * K + kw0 + ko;

  f32x4 acc0 = {}, acc1 = {}, acc2 = {}, acc3 = {};

  // prefetch t=0
  float4 bc0 = *(const float4*)(Bp);
  float4 bc1 = *(const float4*)(Bp + 4);
  short8 ac0 = *(const short8*)(Ap);
  short8 ac1 = *(const short8*)(Ap + 16 * K);
  short8 ac2 = *(const short8*)(Ap + 32 * K);
  short8 ac3 = *(const short8*)(Ap + 48 * K);

  for (int t = 0; t < NK; ++t) {
    float4 bn0 = {}, bn1 = {};
    short8 an0 = {}, an1 = {}, an2 = {}, an3 = {};
    if (t + 1 < NK) {              // issue next k-step loads early
      const float* bp = Bp + (t + 1) * 32;
      const short* ap = Ap + (t + 1) * 32;
      bn0 = *(const float4*)(bp);
      bn1 = *(const float4*)(bp + 4);
      an0 = *(const short8*)(ap);
      an1 = *(const short8*)(ap + 16 * K);
      an2 = *(const short8*)(ap + 32 * K);
      an3 = *(const short8*)(ap + 48 * K);
    }
    short8 bb;
    bb[0] = f2bf(bc0.x); bb[1] = f2bf(bc0.y); bb[2] = f2bf(bc0.z); bb[3] = f2bf(bc0.w);
    bb[4] = f2bf(bc1.x); bb[5] = f2bf(bc1.y); bb[6] = f2bf(bc1.z); bb[7] = f2bf(bc1.w);
    acc0 = __builtin_amdgcn_mfma_f32_16x16x32_bf16(ac0, bb, acc0, 0, 0, 0);
    acc1 = __builtin_amdgcn_mfma_f32_16x16x32_bf16(ac1, bb, acc1, 0, 0, 0);
    acc2 = __builtin_amdgcn_mfma_f32_16x16x32_bf16(ac2, bb, acc2, 0, 0, 0);
    acc3 = __builtin_amdgcn_mfma_f32_16x16x32_bf16(ac3, bb, acc3, 0, 0, 0);
    bc0 = bn0; bc1 = bn1;
    ac0 = an0; ac1 = an1; ac2 = an2; ac3 = an3;
  }

  // wave-partial -> LDS (C/D layout: m = mi*16 + (l>>4)*4 + r, n = l&15)
  {
    float* rw = red + wv * 1024;
    const int mb = (l >> 4) << 2;
    const int nn = l & 15;
#pragma unroll
    for (int r = 0; r < 4; ++r) rw[(0  + mb + r) * 16 + nn] = acc0[r];
#pragma unroll
    for (int r = 0; r < 4; ++r) rw[(16 + mb + r) * 16 + nn] = acc1[r];
#pragma unroll
    for (int r = 0; r < 4; ++r) rw[(32 + mb + r) * 16 + nn] = acc2[r];
#pragma unroll
    for (int r = 0; r < 4; ++r) rw[(48 + mb + r) * 16 + nn] = acc3[r];
  }
  __syncthreads();

  // reduce 8 wave-partials + bias + sigmoid, write final
#pragma unroll
  for (int i = tid; i < 1024; i += 512) {
    float s = 0.f;
#pragma unroll
    for (int w = 0; w < 8; ++w) s += red[w * 1024 + i];
    int m  = i >> 4;
    int nn = n0 + (i & 15);
    s = sigmoidf(s + bias[nn]);
    if constexpr (OUT_BF16) ((short*)outp)[(size_t)m * N + nn] = f2bf(s);
    else                    ((float*)outp)[(size_t)m * N + nn] = s;
  }
}

// --------- einsum partials: fpart[(b*16+cc)*4+p][s] = sum_{c in chunk} w*x --
__global__ __launch_bounds__(256) void einsum_part(const float* __restrict__ x,
                                                   const float* __restrict__ wg,
                                                   float* __restrict__ fpart) {
  const int b  = blockIdx.x >> 4;
  const int cc = blockIdx.x & 15;
  __shared__ float gs[4 * 128];
  const int tid = threadIdx.x;
  const float* wb = wg + (size_t)b * 8192 + cc * 128;
#pragma unroll
  for (int i = 0; i < 2; ++i) {
    int idx = i * 256 + tid;              // p*128 + c
    int p = idx >> 7, c = idx & 127;
    gs[idx] = wb[p * 2048 + c];
  }
  __syncthreads();
  if (tid < 196) {
    const float* xp = x + (size_t)b * 2048 * 196 + (size_t)cc * 128 * 196 + tid;
    float a0 = 0, a1 = 0, a2 = 0, a3 = 0;
#pragma unroll 8
    for (int c = 0; c < 128; ++c) {
      float xv = xp[(size_t)c * 196];
      a0 += gs[c]       * xv;
      a1 += gs[128 + c] * xv;
      a2 += gs[256 + c] * xv;
      a3 += gs[384 + c] * xv;
    }
    float* fp = fpart + ((size_t)(b * 16 + cc) * 4) * 196 + tid;
    fp[0]   = a0;
    fp[196] = a1;
    fp[392] = a2;
    fp[588] = a3;
  }
}

// --------- reduce einsum c-chunk partials, scale by 1/C ---------------------
__global__ __launch_bounds__(256) void feat_reduce(const float* __restrict__ fpart,
                                                   float* __restrict__ feat) {
  int i = blockIdx.x * 256 + threadIdx.x;   // 64*4*196 = 50176 elems
  if (i >= 64 * 4 * 196) return;
  int s = i % 196;
  int p = (i / 196) & 3;
  int b = i / 784;
  float sum = 0.f;
#pragma unroll
  for (int cc = 0; cc < 16; ++cc)
    sum += fpart[((size_t)(b * 16 + cc) * 4 + p) * 196 + s];
  feat[i] = sum * (1.0f / 2048.0f);
}

extern "C" void kernel_launch(void* const* d_in, const int* in_sizes, int n_in,
                              void* d_out, int out_size, void* d_ws, size_t ws_size,
                              hipStream_t stream) {
  const float* x  = (const float*)d_in[0];   // [64,2048,14,14]
  const float* w1 = (const float*)d_in[1];   // [4096,2048]
  const float* b1 = (const float*)d_in[2];   // [4096]
  const float* w2 = (const float*)d_in[3];   // [8192,4096]
  const float* b2 = (const float*)d_in[4];   // [8192]
  float* out = (float*)d_out;

  short* g_bf  = (short*)d_ws;                         // 64*2048 bf16 (256 KB)
  short* h_bf  = g_bf + 64 * 2048;                     // 64*4096 bf16 (512 KB)
  float* fpart = (float*)((char*)d_ws + (1 << 20));    // 64*16*4*196 f32 (3.2 MB)

  float* wout = out;                         // [64, 8192] == [B,P,C] flat
  float* feat = out + 524288;                // [64, 4, 196]

  // 1) pool -> g (bf16): 131072 rows, 4 rows/block -> 32768 blocks
  pool_kernel<<<(64 * 2048) / 4, 256, 0, stream>>>(x, g_bf, 64 * 2048);

  // 2) GEMM1: h = sigmoid(g @ w1^T + b1), bf16 out  (256 blocks x 8 waves)
  gemm_fused<4096, 2048, true><<<4096 / 16, 512, 0, stream>>>(g_bf, w1, b1, h_bf);

  // 3) GEMM2: w = sigmoid(h @ w2^T + b2), f32 out   (512 blocks x 8 waves)
  gemm_fused<8192, 4096, false><<<8192 / 16, 512, 0, stream>>>(h_bf, w2, b2, wout);

  // 4) einsum partials (64 b x 16 c-chunks)
  einsum_part<<<64 * 16, 256, 0, stream>>>(x, wout, fpart);

  // 5) reduce -> feat
  feat_reduce<<<(50176 + 255) / 256, 256, 0, stream>>>(fpart, feat);
}